// Round 4
// baseline (200.832 us; speedup 1.0000x reference)
//
#include <hip/hip_runtime.h>
#include <hip/hip_bf16.h>

typedef __bf16 bf16;
typedef __bf16 bf16x8 __attribute__((ext_vector_type(8)));
typedef __bf16 bf16x4 __attribute__((ext_vector_type(4)));
typedef float  f32x4  __attribute__((ext_vector_type(4)));

#define MFMA16(A, B, C) __builtin_amdgcn_mfma_f32_16x16x32_bf16((A), (B), (C), 0, 0, 0)

static constexpr int Bn = 4;
static constexpr int T  = 4096;
static constexpr int Cd = 1024;
static constexpr int H  = 64;
static constexpr int NG = 192;
static constexpr int CH = 8;            // K-tiles (64 keys each) per split-K chunk
static constexpr int SLOTS_PER_B = 288; // sum_{qt=0..63} ceil((qt+1)/8)
static constexpr float QSCALE = 0.03125f; // 1/sqrt(C) = 1/32, folded into q

__device__ inline bf16x8 cvt_bf16x8(float4 a, float4 b) {
    bf16x8 r;
    r[0] = (bf16)a.x; r[1] = (bf16)a.y; r[2] = (bf16)a.z; r[3] = (bf16)a.w;
    r[4] = (bf16)b.x; r[5] = (bf16)b.y; r[6] = (bf16)b.z; r[7] = (bf16)b.w;
    return r;
}

// ---------------------------------------------------------------------------
// Kernel 1: coalesced transpose W=[Wq|Wk|Wv] ([C][H] fp32) -> Wt[192][1024] bf16
// ---------------------------------------------------------------------------
__global__ __launch_bounds__(256) void wt_kernel(const float* __restrict__ Wq,
                                                 const float* __restrict__ Wk,
                                                 const float* __restrict__ Wv,
                                                 bf16* __restrict__ Wt) {
    __shared__ float s[64][65];
    const int cb = blockIdx.x;
    const int m  = blockIdx.y;
    const float* W = (m == 0) ? Wq : (m == 1) ? Wk : Wv;
    for (int i = threadIdx.x; i < 64 * 64; i += 256) {
        const int c = i >> 6, h = i & 63;
        s[c][h] = W[(cb * 64 + c) * H + h];
    }
    __syncthreads();
    for (int i = threadIdx.x; i < 64 * 64; i += 256) {
        const int n = i >> 6, c = i & 63;
        Wt[(m * 64 + n) * Cd + cb * 64 + c] = (bf16)s[c][n];
    }
}

// ---------------------------------------------------------------------------
// Kernel 2: QKV projection v3. grid = M/16 = 1024 blocks (4/CU), 4 waves.
// All waves share the block's 16 rows (L1/L2 dedup); wave w owns cols
// [48w,48w+48). K-step 64 with explicit next-iter register prefetch of both
// x (4 float4, HBM) and Wt (6 bf16x8, L2). Branchless via clamped address.
// ---------------------------------------------------------------------------
__global__ __launch_bounds__(256, 4) void proj_kernel(const float* __restrict__ x,
                                                      const bf16* __restrict__ Wt,
                                                      bf16* __restrict__ qw,
                                                      bf16* __restrict__ kw,
                                                      bf16* __restrict__ vtw) {
    const int tid  = threadIdx.x;
    const int lane = tid & 63;
    const int w    = tid >> 6;
    const int ml   = lane & 15;
    const int quad = lane >> 4;

    const long r0 = (long)blockIdx.x * 16;

    f32x4 acc[3];
    #pragma unroll
    for (int j = 0; j < 3; ++j) acc[j] = f32x4{0.f, 0.f, 0.f, 0.f};

    const float* xr = x + (r0 + ml) * Cd + quad * 8;
    const bf16*  wb = Wt + (long)(w * 48 + ml) * Cd + quad * 8;

    float4 xc0 = *(const float4*)(xr + 0);
    float4 xc1 = *(const float4*)(xr + 4);
    float4 xc2 = *(const float4*)(xr + 32);
    float4 xc3 = *(const float4*)(xr + 36);
    bf16x8 wc0 = *(const bf16x8*)(wb + 0);
    bf16x8 wc1 = *(const bf16x8*)(wb + 16 * Cd);
    bf16x8 wc2 = *(const bf16x8*)(wb + 32 * Cd);
    bf16x8 wc3 = *(const bf16x8*)(wb + 32);
    bf16x8 wc4 = *(const bf16x8*)(wb + 16 * Cd + 32);
    bf16x8 wc5 = *(const bf16x8*)(wb + 32 * Cd + 32);

    #pragma unroll 4
    for (int kb = 0; kb < Cd; kb += 64) {
        const int kn = (kb < Cd - 64) ? kb + 64 : 0;   // clamp: last iter reloads kb=0
        // prefetch next iteration
        const float4 xn0 = *(const float4*)(xr + kn);
        const float4 xn1 = *(const float4*)(xr + kn + 4);
        const float4 xn2 = *(const float4*)(xr + kn + 32);
        const float4 xn3 = *(const float4*)(xr + kn + 36);
        const bf16x8 wn0 = *(const bf16x8*)(wb + kn);
        const bf16x8 wn1 = *(const bf16x8*)(wb + 16 * Cd + kn);
        const bf16x8 wn2 = *(const bf16x8*)(wb + 32 * Cd + kn);
        const bf16x8 wn3 = *(const bf16x8*)(wb + kn + 32);
        const bf16x8 wn4 = *(const bf16x8*)(wb + 16 * Cd + kn + 32);
        const bf16x8 wn5 = *(const bf16x8*)(wb + 32 * Cd + kn + 32);

        const bf16x8 af0 = cvt_bf16x8(xc0, xc1);
        const bf16x8 af1 = cvt_bf16x8(xc2, xc3);
        acc[0] = MFMA16(af0, wc0, acc[0]);
        acc[1] = MFMA16(af0, wc1, acc[1]);
        acc[2] = MFMA16(af0, wc2, acc[2]);
        acc[0] = MFMA16(af1, wc3, acc[0]);
        acc[1] = MFMA16(af1, wc4, acc[1]);
        acc[2] = MFMA16(af1, wc5, acc[2]);

        xc0 = xn0; xc1 = xn1; xc2 = xn2; xc3 = xn3;
        wc0 = wn0; wc1 = wn1; wc2 = wn2; wc3 = wn3; wc4 = wn4; wc5 = wn5;
    }

    const int b = (int)(r0 >> 12);
    const long rowb = r0 + quad * 4;
    const int  tloc = (int)(rowb & 4095);

    #pragma unroll
    for (int f = 0; f < 3; ++f) {
        const int base = w * 48 + f * 16;
        const int sel  = base >> 6;
        const int h    = (base & 63) + ml;
        if (sel == 0) {
            #pragma unroll
            for (int rr = 0; rr < 4; ++rr)
                qw[(rowb + rr) * H + h] = (bf16)(acc[f][rr] * QSCALE);
        } else if (sel == 1) {
            #pragma unroll
            for (int rr = 0; rr < 4; ++rr)
                kw[(rowb + rr) * H + h] = (bf16)acc[f][rr];
        } else {
            bf16x4 pv;
            #pragma unroll
            for (int rr = 0; rr < 4; ++rr) pv[rr] = (bf16)acc[f][rr];
            *(bf16x4*)(vtw + ((long)(b * H + h)) * T + tloc) = pv;
        }
    }
}

// ---------------------------------------------------------------------------
// Kernel 3: split-K causal flash chunk v2 with K/V register prefetch.
// grid (64 qt, 8 chunk, 4 b), 256 thr. Per iter: barrier, store prefetched
// regs -> LDS, issue next tile's loads, barrier, compute (latency hidden).
// ---------------------------------------------------------------------------
__global__ __launch_bounds__(256, 4) void attn_kernel(const bf16* __restrict__ qw,
                                                      const bf16* __restrict__ kw,
                                                      const bf16* __restrict__ vtw,
                                                      float* __restrict__ pO,
                                                      float* __restrict__ pL) {
    const int qt = blockIdx.x;
    const int c  = blockIdx.y;
    const int b  = blockIdx.z;
    const int g  = qt >> 3, r = qt & 7;
    if (c > g) return;

    const int tid  = threadIdx.x;
    const int lane = tid & 63;
    const int w    = tid >> 6;
    const int ml   = lane & 15;
    const int quad = lane >> 4;

    __shared__ bf16 sK[64][72];
    __shared__ bf16 sVt[64][72];
    __shared__ bf16 sP[4][16][72];

    const int t0 = qt * 64;

    const bf16* q0 = qw + ((long)b * T + t0 + w * 16 + ml) * H;
    const bf16x8 aq0 = *(const bf16x8*)(q0 + quad * 8);
    const bf16x8 aq1 = *(const bf16x8*)(q0 + 32 + quad * 8);

    f32x4 O[4];
    #pragma unroll
    for (int ht = 0; ht < 4; ++ht) O[ht] = f32x4{0.f, 0.f, 0.f, 0.f};
    float lrow[4] = {0.f, 0.f, 0.f, 0.f};

    const int trow = t0 + w * 16 + quad * 4;
    const int jt0 = c * CH;
    const int jt1 = (c == g) ? qt + 1 : (c + 1) * CH;

    // per-thread staging slots: rows tid>>3 and 32+(tid>>3), col group (tid&7)*8
    const int rowA = tid >> 3;
    const int rowB = rowA + 32;
    const int cg8  = (tid & 7) * 8;
    const bf16* kbase = kw + (long)b * T * H;
    const bf16* vbase = vtw + (long)b * H * T;
    const long koffA = (long)rowA * H + cg8;
    const long koffB = (long)rowB * H + cg8;
    const long voffA = (long)rowA * T + cg8;
    const long voffB = (long)rowB * T + cg8;

    uint4 kr0 = *(const uint4*)(kbase + (long)jt0 * 64 * H + koffA);
    uint4 kr1 = *(const uint4*)(kbase + (long)jt0 * 64 * H + koffB);
    uint4 vr0 = *(const uint4*)(vbase + jt0 * 64 + voffA);
    uint4 vr1 = *(const uint4*)(vbase + jt0 * 64 + voffB);

    for (int jt = jt0; jt < jt1; ++jt) {
        __syncthreads();                 // prev iter's sK/sVt reads drained
        *(uint4*)&sK[rowA][cg8]  = kr0;
        *(uint4*)&sK[rowB][cg8]  = kr1;
        *(uint4*)&sVt[rowA][cg8] = vr0;
        *(uint4*)&sVt[rowB][cg8] = vr1;
        // issue next tile's loads now; consumed next iteration
        const int jn = (jt + 1 < jt1) ? jt + 1 : jt;
        kr0 = *(const uint4*)(kbase + (long)jn * 64 * H + koffA);
        kr1 = *(const uint4*)(kbase + (long)jn * 64 * H + koffB);
        vr0 = *(const uint4*)(vbase + jn * 64 + voffA);
        vr1 = *(const uint4*)(vbase + jn * 64 + voffB);
        __syncthreads();

        const int s0 = jt * 64;
        const bool diag = (jt == qt);
        #pragma unroll
        for (int nt = 0; nt < 4; ++nt) {
            f32x4 sacc = f32x4{0.f, 0.f, 0.f, 0.f};
            sacc = MFMA16(aq0, *(const bf16x8*)&sK[nt * 16 + ml][quad * 8], sacc);
            sacc = MFMA16(aq1, *(const bf16x8*)&sK[nt * 16 + ml][32 + quad * 8], sacc);
            const int col = s0 + nt * 16 + ml;
            #pragma unroll
            for (int rr = 0; rr < 4; ++rr) {
                const float p = (diag && col > trow + rr) ? 0.f : __expf(sacc[rr]);
                lrow[rr] += p;
                sP[w][quad * 4 + rr][nt * 16 + ml] = (bf16)p;
            }
        }
        asm volatile("s_waitcnt lgkmcnt(0)" ::: "memory");  // wave-private sP RAW

        #pragma unroll
        for (int ks = 0; ks < 2; ++ks) {
            const bf16x8 ap = *(const bf16x8*)&sP[w][ml][ks * 32 + quad * 8];
            #pragma unroll
            for (int ht = 0; ht < 4; ++ht)
                O[ht] = MFMA16(ap, *(const bf16x8*)&sVt[ht * 16 + ml][ks * 32 + quad * 8], O[ht]);
        }
    }

    #pragma unroll
    for (int d = 1; d < 16; d <<= 1)
        #pragma unroll
        for (int rr = 0; rr < 4; ++rr)
            lrow[rr] += __shfl_xor(lrow[rr], d, 64);

    const long slot = (long)b * SLOTS_PER_B + (long)(g + 1) * (4 * g + r) + c;
    float* po = pO + slot * 4096 + (w * 16) * 64;
    #pragma unroll
    for (int ht = 0; ht < 4; ++ht)
        #pragma unroll
        for (int rr = 0; rr < 4; ++rr)
            po[(quad * 4 + rr) * 64 + ht * 16 + ml] = O[ht][rr];
    if (ml == 0) {
        #pragma unroll
        for (int rr = 0; rr < 4; ++rr)
            pL[slot * 64 + w * 16 + quad * 4 + rr] = lrow[rr];
    }
}

// ---------------------------------------------------------------------------
// Kernel 4: combine partials. grid (64 qt, 4 b), 256 thr.
// ---------------------------------------------------------------------------
__global__ __launch_bounds__(256) void combine_kernel(const float* __restrict__ pO,
                                                      const float* __restrict__ pL,
                                                      float* __restrict__ out) {
    const int qt = blockIdx.x;
    const int b  = blockIdx.y;
    const int g  = qt >> 3, r = qt & 7;
    const int nch = g + 1;
    const long slot0 = (long)b * SLOTS_PER_B + (long)(g + 1) * (4 * g + r);

    const int tid = threadIdx.x;
    const int row = tid >> 2;
    const int q4  = tid & 3;

    f32x4 o[4];
    #pragma unroll
    for (int j = 0; j < 4; ++j) o[j] = f32x4{0.f, 0.f, 0.f, 0.f};
    float l = 0.f;

    for (int cc = 0; cc < nch; ++cc) {
        const float* po = pO + (slot0 + cc) * 4096 + row * 64 + q4 * 16;
        #pragma unroll
        for (int j = 0; j < 4; ++j) o[j] += *(const f32x4*)(po + j * 4);
        l += pL[(slot0 + cc) * 64 + row];
    }
    const float inv = 1.f / l;
    float* op = out + ((long)b * T + qt * 64 + row) * H + q4 * 16;
    #pragma unroll
    for (int j = 0; j < 4; ++j) {
        f32x4 v = o[j];
        v[0] *= inv; v[1] *= inv; v[2] *= inv; v[3] *= inv;
        *(f32x4*)(op + j * 4) = v;
    }
}

// ---------------------------------------------------------------------------
extern "C" void kernel_launch(void* const* d_in, const int* in_sizes, int n_in,
                              void* d_out, int out_size, void* d_ws, size_t ws_size,
                              hipStream_t stream) {
    const float* x  = (const float*)d_in[0];
    const float* Wq = (const float*)d_in[1];
    const float* Wk = (const float*)d_in[2];
    const float* Wv = (const float*)d_in[3];
    float* out = (float*)d_out;

    char* ws = (char*)d_ws;
    const size_t WT_BYTES = (size_t)NG * Cd * sizeof(bf16);
    const size_t QK_BYTES = (size_t)Bn * T * H * sizeof(bf16);
    const size_t PO_OFF   = WT_BYTES + 3 * QK_BYTES;
    const size_t PO_BYTES = (size_t)Bn * SLOTS_PER_B * 4096 * sizeof(float);
    bf16*  Wt  = (bf16*)ws;
    bf16*  qw  = (bf16*)(ws + WT_BYTES);
    bf16*  kw  = (bf16*)(ws + WT_BYTES + QK_BYTES);
    bf16*  vtw = (bf16*)(ws + WT_BYTES + 2 * QK_BYTES);
    float* pO  = (float*)(ws + PO_OFF);
    float* pL  = (float*)(ws + PO_OFF + PO_BYTES);

    wt_kernel<<<dim3(16, 3), dim3(256), 0, stream>>>(Wq, Wk, Wv, Wt);
    proj_kernel<<<dim3((Bn * T) / 16), dim3(256), 0, stream>>>(x, Wt, qw, kw, vtw);
    attn_kernel<<<dim3(T / 64, CH, Bn), dim3(256), 0, stream>>>(qw, kw, vtw, pO, pL);
    combine_kernel<<<dim3(T / 64, Bn), dim3(256), 0, stream>>>(pO, pL, out);
}

// Round 5
// 178.624 us; speedup vs baseline: 1.1243x; 1.1243x over previous
//
#include <hip/hip_runtime.h>
#include <hip/hip_bf16.h>

typedef __bf16 bf16;
typedef __bf16 bf16x8 __attribute__((ext_vector_type(8)));
typedef __bf16 bf16x4 __attribute__((ext_vector_type(4)));
typedef float  f32x4  __attribute__((ext_vector_type(4)));

#define MFMA16(A, B, C) __builtin_amdgcn_mfma_f32_16x16x32_bf16((A), (B), (C), 0, 0, 0)

static constexpr int Bn = 4;
static constexpr int T  = 4096;
static constexpr int Cd = 1024;
static constexpr int H  = 64;
static constexpr int NG = 192;
static constexpr int CH = 8;            // K-tiles (64 keys each) per split-K chunk
static constexpr int SLOTS_PER_B = 288; // sum_{qt=0..63} ceil((qt+1)/8)
static constexpr float QSCALE = 0.03125f; // 1/sqrt(C) = 1/32, folded into q

// async global->LDS DMA, 16B per lane; LDS dest = wave-uniform base + lane*16
__device__ inline void dma16(const void* g, void* l) {
    __builtin_amdgcn_global_load_lds(
        (const __attribute__((address_space(1))) unsigned int*)g,
        (__attribute__((address_space(3))) unsigned int*)l, 16, 0, 0);
}

__device__ inline bf16x8 cvt_bf16x8(float4 a, float4 b) {
    bf16x8 r;
    r[0] = (bf16)a.x; r[1] = (bf16)a.y; r[2] = (bf16)a.z; r[3] = (bf16)a.w;
    r[4] = (bf16)b.x; r[5] = (bf16)b.y; r[6] = (bf16)b.z; r[7] = (bf16)b.w;
    return r;
}

// ---------------------------------------------------------------------------
// Kernel 1: coalesced transpose W=[Wq|Wk|Wv] ([C][H] fp32) -> Wt[192][1024] bf16
// ---------------------------------------------------------------------------
__global__ __launch_bounds__(256) void wt_kernel(const float* __restrict__ Wq,
                                                 const float* __restrict__ Wk,
                                                 const float* __restrict__ Wv,
                                                 bf16* __restrict__ Wt) {
    __shared__ float s[64][65];
    const int cb = blockIdx.x;
    const int m  = blockIdx.y;
    const float* W = (m == 0) ? Wq : (m == 1) ? Wk : Wv;
    for (int i = threadIdx.x; i < 64 * 64; i += 256) {
        const int c = i >> 6, h = i & 63;
        s[c][h] = W[(cb * 64 + c) * H + h];
    }
    __syncthreads();
    for (int i = threadIdx.x; i < 64 * 64; i += 256) {
        const int n = i >> 6, c = i & 63;
        Wt[(m * 64 + n) * Cd + cb * 64 + c] = (bf16)s[c][n];
    }
}

// ---------------------------------------------------------------------------
// Kernel 2: QKV projection v5. grid = M/16 = 1024 blocks (4/CU), 4 waves.
// x staged via global_load_lds DMA into double-buffered LDS, XOR-swizzled
// 16B chunks (chunk c of row r holds global chunk c^r -> conflict-free b128
// frag reads without padding). Wave w owns cols [48w,48w+48).
// ---------------------------------------------------------------------------
__global__ __launch_bounds__(256, 4) void proj_kernel(const float* __restrict__ x,
                                                      const bf16* __restrict__ Wt,
                                                      bf16* __restrict__ qw,
                                                      bf16* __restrict__ kw,
                                                      bf16* __restrict__ vtw) {
    const int tid  = threadIdx.x;
    const int lane = tid & 63;
    const int w    = tid >> 6;
    const int ml   = lane & 15;
    const int quad = lane >> 4;

    const long r0 = (long)blockIdx.x * 16;

    __shared__ float sX[2][16][64];      // 4 KB per buffer, swizzled

    // DMA mapping: lane covers row = w*4 + (lane>>4), 16B chunk = lane&15
    const int drow = w * 4 + (lane >> 4);
    const int dchk = lane & 15;
    const float* gx = x + (r0 + drow) * Cd + ((dchk ^ drow) << 2);

    f32x4 acc[3];
    #pragma unroll
    for (int j = 0; j < 3; ++j) acc[j] = f32x4{0.f, 0.f, 0.f, 0.f};

    const bf16* wb = Wt + (long)(w * 48 + ml) * Cd + quad * 8;

    // prologue: stage tile kb=0
    dma16(gx, &sX[0][w * 4][0]);
    __syncthreads();

    int buf = 0;
    for (int kb = 0; kb < Cd; kb += 64) {
        if (kb + 64 < Cd)                          // prefetch next tile
            dma16(gx + kb + 64, &sX[buf ^ 1][w * 4][0]);

        // Wt B-frags for this K-64 (L2-resident)
        const bf16x8 w00 = *(const bf16x8*)(wb + kb);
        const bf16x8 w01 = *(const bf16x8*)(wb + 16 * Cd + kb);
        const bf16x8 w02 = *(const bf16x8*)(wb + 32 * Cd + kb);
        const bf16x8 w10 = *(const bf16x8*)(wb + kb + 32);
        const bf16x8 w11 = *(const bf16x8*)(wb + 16 * Cd + kb + 32);
        const bf16x8 w12 = *(const bf16x8*)(wb + 32 * Cd + kb + 32);

        // A-frags from swizzled LDS: ks-half, chunks g0=ks*8+2q, g0+1
        const int c00 = (0 * 8 + quad * 2) ^ ml;
        const int c10 = (1 * 8 + quad * 2) ^ ml;
        const float4 lo0 = *(const float4*)&sX[buf][ml][c00 << 2];
        const float4 hi0 = *(const float4*)&sX[buf][ml][(c00 ^ 1) << 2];
        const float4 lo1 = *(const float4*)&sX[buf][ml][c10 << 2];
        const float4 hi1 = *(const float4*)&sX[buf][ml][(c10 ^ 1) << 2];
        const bf16x8 af0 = cvt_bf16x8(lo0, hi0);
        const bf16x8 af1 = cvt_bf16x8(lo1, hi1);

        acc[0] = MFMA16(af0, w00, acc[0]);
        acc[1] = MFMA16(af0, w01, acc[1]);
        acc[2] = MFMA16(af0, w02, acc[2]);
        acc[0] = MFMA16(af1, w10, acc[0]);
        acc[1] = MFMA16(af1, w11, acc[1]);
        acc[2] = MFMA16(af1, w12, acc[2]);

        __syncthreads();                            // next tile ready; reads drained
        buf ^= 1;
    }

    const int b = (int)(r0 >> 12);
    const long rowb = r0 + quad * 4;
    const int  tloc = (int)(rowb & 4095);

    #pragma unroll
    for (int f = 0; f < 3; ++f) {
        const int base = w * 48 + f * 16;
        const int sel  = base >> 6;
        const int h    = (base & 63) + ml;
        if (sel == 0) {
            #pragma unroll
            for (int rr = 0; rr < 4; ++rr)
                qw[(rowb + rr) * H + h] = (bf16)(acc[f][rr] * QSCALE);
        } else if (sel == 1) {
            #pragma unroll
            for (int rr = 0; rr < 4; ++rr)
                kw[(rowb + rr) * H + h] = (bf16)acc[f][rr];
        } else {
            bf16x4 pv;
            #pragma unroll
            for (int rr = 0; rr < 4; ++rr) pv[rr] = (bf16)acc[f][rr];
            *(bf16x4*)(vtw + ((long)(b * H + h)) * T + tloc) = pv;
        }
    }
}

// ---------------------------------------------------------------------------
// Kernel 3: split-K causal flash chunk v3. K/V tiles staged via DMA into
// double-buffered unpadded LDS with 3-bit XOR chunk swizzle. One barrier/iter.
// grid (64 qt, 8 chunk, 4 b), 256 thr, 3 blocks/CU (41 KB LDS).
// ---------------------------------------------------------------------------
__global__ __launch_bounds__(256, 3) void attn_kernel(const bf16* __restrict__ qw,
                                                      const bf16* __restrict__ kw,
                                                      const bf16* __restrict__ vtw,
                                                      float* __restrict__ pO,
                                                      float* __restrict__ pL) {
    const int qt = blockIdx.x;
    const int c  = blockIdx.y;
    const int b  = blockIdx.z;
    const int g  = qt >> 3, r = qt & 7;
    if (c > g) return;

    const int tid  = threadIdx.x;
    const int lane = tid & 63;
    const int w    = tid >> 6;
    const int ml   = lane & 15;
    const int quad = lane >> 4;
    const int mx   = ml & 7;

    __shared__ bf16 sK[2][64][64];      // swizzled, 8 KB per buffer
    __shared__ bf16 sVt[2][64][64];     // swizzled
    __shared__ bf16 sP[4][16][72];      // padded (normal ds_write)

    const int t0 = qt * 64;

    const bf16* q0 = qw + ((long)b * T + t0 + w * 16 + ml) * H;
    const bf16x8 aq0 = *(const bf16x8*)(q0 + quad * 8);
    const bf16x8 aq1 = *(const bf16x8*)(q0 + 32 + quad * 8);

    f32x4 O[4];
    #pragma unroll
    for (int ht = 0; ht < 4; ++ht) O[ht] = f32x4{0.f, 0.f, 0.f, 0.f};
    float lrow[4] = {0.f, 0.f, 0.f, 0.f};

    const int trow = t0 + w * 16 + quad * 4;
    const int jt0 = c * CH;
    const int jt1 = (c == g) ? qt + 1 : (c + 1) * CH;

    // DMA mapping: per 32-row group, lane covers row w*8+(lane>>3), chunk lane&7
    const int drow = w * 8 + (lane >> 3);             // 0..31
    const int dsw  = ((lane & 7) ^ (drow & 7)) << 3;  // swizzled elem offset
    const bf16* kbase = kw + (long)b * T * H;
    const bf16* vbase = vtw + (long)b * H * T;
    const long koffA = (long)drow * H + dsw;
    const long koffB = koffA + 32 * H;
    const long voffA = (long)drow * T + dsw;
    const long voffB = voffA + (long)32 * T;

    // prologue: stage tile jt0 into buf 0
    {
        const long ks0 = (long)jt0 * 64;
        dma16(kbase + ks0 * H + koffA, &sK[0][w * 8][0]);
        dma16(kbase + ks0 * H + koffB, &sK[0][32 + w * 8][0]);
        dma16(vbase + ks0 + voffA, &sVt[0][w * 8][0]);
        dma16(vbase + ks0 + voffB, &sVt[0][32 + w * 8][0]);
    }
    __syncthreads();

    int buf = 0;
    for (int jt = jt0; jt < jt1; ++jt) {
        if (jt + 1 < jt1) {                         // prefetch next tile
            const long ksn = (long)(jt + 1) * 64;
            dma16(kbase + ksn * H + koffA, &sK[buf ^ 1][w * 8][0]);
            dma16(kbase + ksn * H + koffB, &sK[buf ^ 1][32 + w * 8][0]);
            dma16(vbase + ksn + voffA, &sVt[buf ^ 1][w * 8][0]);
            dma16(vbase + ksn + voffB, &sVt[buf ^ 1][32 + w * 8][0]);
        }

        const int s0 = jt * 64;
        const bool diag = (jt == qt);
        #pragma unroll
        for (int nt = 0; nt < 4; ++nt) {
            f32x4 sacc = f32x4{0.f, 0.f, 0.f, 0.f};
            sacc = MFMA16(aq0, *(const bf16x8*)&sK[buf][nt * 16 + ml][(quad ^ mx) << 3], sacc);
            sacc = MFMA16(aq1, *(const bf16x8*)&sK[buf][nt * 16 + ml][((4 + quad) ^ mx) << 3], sacc);
            const int col = s0 + nt * 16 + ml;
            #pragma unroll
            for (int rr = 0; rr < 4; ++rr) {
                const float p = (diag && col > trow + rr) ? 0.f : __expf(sacc[rr]);
                lrow[rr] += p;
                sP[w][quad * 4 + rr][nt * 16 + ml] = (bf16)p;
            }
        }
        asm volatile("s_waitcnt lgkmcnt(0)" ::: "memory");  // wave-private sP RAW

        #pragma unroll
        for (int ks = 0; ks < 2; ++ks) {
            const bf16x8 ap = *(const bf16x8*)&sP[w][ml][ks * 32 + quad * 8];
            #pragma unroll
            for (int ht = 0; ht < 4; ++ht)
                O[ht] = MFMA16(ap,
                    *(const bf16x8*)&sVt[buf][ht * 16 + ml][(((ks << 2) + quad) ^ mx) << 3],
                    O[ht]);
        }

        __syncthreads();                            // next tile ready; reads drained
        buf ^= 1;
    }

    #pragma unroll
    for (int d = 1; d < 16; d <<= 1)
        #pragma unroll
        for (int rr = 0; rr < 4; ++rr)
            lrow[rr] += __shfl_xor(lrow[rr], d, 64);

    const long slot = (long)b * SLOTS_PER_B + (long)(g + 1) * (4 * g + r) + c;
    float* po = pO + slot * 4096 + (w * 16) * 64;
    #pragma unroll
    for (int ht = 0; ht < 4; ++ht)
        #pragma unroll
        for (int rr = 0; rr < 4; ++rr)
            po[(quad * 4 + rr) * 64 + ht * 16 + ml] = O[ht][rr];
    if (ml == 0) {
        #pragma unroll
        for (int rr = 0; rr < 4; ++rr)
            pL[slot * 64 + w * 16 + quad * 4 + rr] = lrow[rr];
    }
}

// ---------------------------------------------------------------------------
// Kernel 4: combine partials. grid (64 qt, 4 b), 256 thr.
// ---------------------------------------------------------------------------
__global__ __launch_bounds__(256) void combine_kernel(const float* __restrict__ pO,
                                                      const float* __restrict__ pL,
                                                      float* __restrict__ out) {
    const int qt = blockIdx.x;
    const int b  = blockIdx.y;
    const int g  = qt >> 3, r = qt & 7;
    const int nch = g + 1;
    const long slot0 = (long)b * SLOTS_PER_B + (long)(g + 1) * (4 * g + r);

    const int tid = threadIdx.x;
    const int row = tid >> 2;
    const int q4  = tid & 3;

    f32x4 o[4];
    #pragma unroll
    for (int j = 0; j < 4; ++j) o[j] = f32x4{0.f, 0.f, 0.f, 0.f};
    float l = 0.f;

    for (int cc = 0; cc < nch; ++cc) {
        const float* po = pO + (slot0 + cc) * 4096 + row * 64 + q4 * 16;
        #pragma unroll
        for (int j = 0; j < 4; ++j) o[j] += *(const f32x4*)(po + j * 4);
        l += pL[(slot0 + cc) * 64 + row];
    }
    const float inv = 1.f / l;
    float* op = out + ((long)b * T + qt * 64 + row) * H + q4 * 16;
    #pragma unroll
    for (int j = 0; j < 4; ++j) {
        f32x4 v = o[j];
        v[0] *= inv; v[1] *= inv; v[2] *= inv; v[3] *= inv;
        *(f32x4*)(op + j * 4) = v;
    }
}

// ---------------------------------------------------------------------------
extern "C" void kernel_launch(void* const* d_in, const int* in_sizes, int n_in,
                              void* d_out, int out_size, void* d_ws, size_t ws_size,
                              hipStream_t stream) {
    const float* x  = (const float*)d_in[0];
    const float* Wq = (const float*)d_in[1];
    const float* Wk = (const float*)d_in[2];
    const float* Wv = (const float*)d_in[3];
    float* out = (float*)d_out;

    char* ws = (char*)d_ws;
    const size_t WT_BYTES = (size_t)NG * Cd * sizeof(bf16);
    const size_t QK_BYTES = (size_t)Bn * T * H * sizeof(bf16);
    const size_t PO_OFF   = WT_BYTES + 3 * QK_BYTES;
    const size_t PO_BYTES = (size_t)Bn * SLOTS_PER_B * 4096 * sizeof(float);
    bf16*  Wt  = (bf16*)ws;
    bf16*  qw  = (bf16*)(ws + WT_BYTES);
    bf16*  kw  = (bf16*)(ws + WT_BYTES + QK_BYTES);
    bf16*  vtw = (bf16*)(ws + WT_BYTES + 2 * QK_BYTES);
    float* pO  = (float*)(ws + PO_OFF);
    float* pL  = (float*)(ws + PO_OFF + PO_BYTES);

    wt_kernel<<<dim3(16, 3), dim3(256), 0, stream>>>(Wq, Wk, Wv, Wt);
    proj_kernel<<<dim3((Bn * T) / 16), dim3(256), 0, stream>>>(x, Wt, qw, kw, vtw);
    attn_kernel<<<dim3(T / 64, CH, Bn), dim3(256), 0, stream>>>(qw, kw, vtw, pO, pL);
    combine_kernel<<<dim3(T / 64, Bn), dim3(256), 0, stream>>>(pO, pL, out);
}

// Round 6
// 153.373 us; speedup vs baseline: 1.3094x; 1.1646x over previous
//
#include <hip/hip_runtime.h>
#include <hip/hip_bf16.h>

typedef __bf16 bf16;
typedef __bf16 bf16x8 __attribute__((ext_vector_type(8)));
typedef __bf16 bf16x4 __attribute__((ext_vector_type(4)));
typedef float  f32x4  __attribute__((ext_vector_type(4)));

#define MFMA16(A, B, C) __builtin_amdgcn_mfma_f32_16x16x32_bf16((A), (B), (C), 0, 0, 0)

static constexpr int Bn = 4;
static constexpr int T  = 4096;
static constexpr int Cd = 1024;
static constexpr int H  = 64;
static constexpr int NG = 192;
static constexpr int CH = 8;            // K-tiles (64 keys each) per split-K chunk
static constexpr int SLOTS_PER_B = 288; // sum_{qt=0..63} ceil((qt+1)/8)
static constexpr float QSCALE = 0.03125f; // 1/sqrt(C) = 1/32, folded into q

// async global->LDS DMA, 16B per lane; LDS dest = wave-uniform base + lane*16
__device__ inline void dma16(const void* g, void* l) {
    __builtin_amdgcn_global_load_lds(
        (const __attribute__((address_space(1))) unsigned int*)g,
        (__attribute__((address_space(3))) unsigned int*)l, 16, 0, 0);
}

__device__ inline bf16x8 cvt_bf16x8(float4 a, float4 b) {
    bf16x8 r;
    r[0] = (bf16)a.x; r[1] = (bf16)a.y; r[2] = (bf16)a.z; r[3] = (bf16)a.w;
    r[4] = (bf16)b.x; r[5] = (bf16)b.y; r[6] = (bf16)b.z; r[7] = (bf16)b.w;
    return r;
}

// ---------------------------------------------------------------------------
// Kernel 1: coalesced transpose W=[Wq|Wk|Wv] ([C][H] fp32) -> Wt[192][1024] bf16
// ---------------------------------------------------------------------------
__global__ __launch_bounds__(256) void wt_kernel(const float* __restrict__ Wq,
                                                 const float* __restrict__ Wk,
                                                 const float* __restrict__ Wv,
                                                 bf16* __restrict__ Wt) {
    __shared__ float s[64][65];
    const int cb = blockIdx.x;
    const int m  = blockIdx.y;
    const float* W = (m == 0) ? Wq : (m == 1) ? Wk : Wv;
    for (int i = threadIdx.x; i < 64 * 64; i += 256) {
        const int c = i >> 6, h = i & 63;
        s[c][h] = W[(cb * 64 + c) * H + h];
    }
    __syncthreads();
    for (int i = threadIdx.x; i < 64 * 64; i += 256) {
        const int n = i >> 6, c = i & 63;
        Wt[(m * 64 + n) * Cd + cb * 64 + c] = (bf16)s[c][n];
    }
}

// ---------------------------------------------------------------------------
// Kernel 2: QKV projection v6. grid = M/32 = 512 blocks, 512 thr = 8 waves
// in a 2x4 layout: wave (wr,wc) computes rows [wr*16,+16) x cols [wc*48,+48).
// BOTH x and Wt K-tiles staged via global_load_lds DMA into double-buffered
// XOR-swizzled LDS (no VGPR loads in the K-loop -> compiler can't serialize).
// ---------------------------------------------------------------------------
__global__ __launch_bounds__(512, 4) void proj_kernel(const float* __restrict__ x,
                                                      const bf16* __restrict__ Wt,
                                                      bf16* __restrict__ qw,
                                                      bf16* __restrict__ kw,
                                                      bf16* __restrict__ vtw) {
    const int tid  = threadIdx.x;
    const int lane = tid & 63;
    const int w    = tid >> 6;       // 0..7
    const int wr   = w >> 2;         // 0..1 row-group
    const int wc   = w & 3;          // 0..3 col-group
    const int ml   = lane & 15;
    const int quad = lane >> 4;

    const long r0 = (long)blockIdx.x * 32;

    __shared__ float sX[2][32][64];   // 8 KB/buf, 16B chunks swizzled c^(r&15)
    __shared__ bf16  sW[2][192][64];  // 24 KB/buf, 16B chunks swizzled c^(r&7)

    // x DMA mapping: wave w covers rows w*4+(lane>>4), chunk lane&15
    const int xrow = w * 4 + (lane >> 4);           // 0..31
    const float* gx = x + (r0 + xrow) * Cd + (((lane & 15) ^ (xrow & 15)) << 2);
    // Wt DMA mapping: 3 instrs; instr i covers rows w*24+i*8+(lane>>3), chunk lane&7
    const int wchunk = ((lane & 7) ^ (lane >> 3)) << 3;   // elem offset in tile
    const bf16* gw0 = Wt + (long)(w * 24 + 0 + (lane >> 3)) * Cd + wchunk;
    const bf16* gw1 = Wt + (long)(w * 24 + 8 + (lane >> 3)) * Cd + wchunk;
    const bf16* gw2 = Wt + (long)(w * 24 + 16 + (lane >> 3)) * Cd + wchunk;

    f32x4 acc[3];
    #pragma unroll
    for (int j = 0; j < 3; ++j) acc[j] = f32x4{0.f, 0.f, 0.f, 0.f};

    // prologue: stage tile kb=0 into buf 0
    dma16(gx, &sX[0][w * 4][0]);
    dma16(gw0, &sW[0][w * 24 + 0][0]);
    dma16(gw1, &sW[0][w * 24 + 8][0]);
    dma16(gw2, &sW[0][w * 24 + 16][0]);
    __syncthreads();

    const int arow = wr * 16 + ml;                  // A row in tile
    const int brow0 = wc * 48 + ml;                 // B rows in tile (f*16 +)
    const int bsw = ml & 7;

    int buf = 0;
    for (int kb = 0; kb < Cd; kb += 64) {
        if (kb + 64 < Cd) {
            dma16(gx + kb + 64, &sX[buf ^ 1][w * 4][0]);
            dma16(gw0 + kb + 64, &sW[buf ^ 1][w * 24 + 0][0]);
            dma16(gw1 + kb + 64, &sW[buf ^ 1][w * 24 + 8][0]);
            dma16(gw2 + kb + 64, &sW[buf ^ 1][w * 24 + 16][0]);
        }

        #pragma unroll
        for (int ks = 0; ks < 2; ++ks) {
            const int ca = (ks * 8 + quad * 2) ^ ml;       // A chunk (of 16)
            const float4 lo = *(const float4*)&sX[buf][arow][ca << 2];
            const float4 hi = *(const float4*)&sX[buf][arow][(ca ^ 1) << 2];
            const bf16x8 af = cvt_bf16x8(lo, hi);
            const int cb0 = (ks * 4 + quad) ^ bsw;         // B chunk (of 8)
            acc[0] = MFMA16(af, *(const bf16x8*)&sW[buf][brow0 + 0][cb0 << 3], acc[0]);
            acc[1] = MFMA16(af, *(const bf16x8*)&sW[buf][brow0 + 16][cb0 << 3], acc[1]);
            acc[2] = MFMA16(af, *(const bf16x8*)&sW[buf][brow0 + 32][cb0 << 3], acc[2]);
        }

        __syncthreads();          // next tile staged; this tile's reads drained
        buf ^= 1;
    }

    const int b = (int)(r0 >> 12);
    const long rowb = r0 + wr * 16 + quad * 4;
    const int  tloc = (int)(rowb & 4095);

    #pragma unroll
    for (int f = 0; f < 3; ++f) {
        const int base = wc * 48 + f * 16;
        const int sel  = base >> 6;
        const int h    = (base & 63) + ml;
        if (sel == 0) {
            #pragma unroll
            for (int rr = 0; rr < 4; ++rr)
                qw[(rowb + rr) * H + h] = (bf16)(acc[f][rr] * QSCALE);
        } else if (sel == 1) {
            #pragma unroll
            for (int rr = 0; rr < 4; ++rr)
                kw[(rowb + rr) * H + h] = (bf16)acc[f][rr];
        } else {
            bf16x4 pv;
            #pragma unroll
            for (int rr = 0; rr < 4; ++rr) pv[rr] = (bf16)acc[f][rr];
            *(bf16x4*)(vtw + ((long)(b * H + h)) * T + tloc) = pv;
        }
    }
}

// ---------------------------------------------------------------------------
// Kernel 3: split-K causal flash chunk v3 (unchanged from R5).
// ---------------------------------------------------------------------------
__global__ __launch_bounds__(256, 3) void attn_kernel(const bf16* __restrict__ qw,
                                                      const bf16* __restrict__ kw,
                                                      const bf16* __restrict__ vtw,
                                                      float* __restrict__ pO,
                                                      float* __restrict__ pL) {
    const int qt = blockIdx.x;
    const int c  = blockIdx.y;
    const int b  = blockIdx.z;
    const int g  = qt >> 3, r = qt & 7;
    if (c > g) return;

    const int tid  = threadIdx.x;
    const int lane = tid & 63;
    const int w    = tid >> 6;
    const int ml   = lane & 15;
    const int quad = lane >> 4;
    const int mx   = ml & 7;

    __shared__ bf16 sK[2][64][64];
    __shared__ bf16 sVt[2][64][64];
    __shared__ bf16 sP[4][16][72];

    const int t0 = qt * 64;

    const bf16* q0 = qw + ((long)b * T + t0 + w * 16 + ml) * H;
    const bf16x8 aq0 = *(const bf16x8*)(q0 + quad * 8);
    const bf16x8 aq1 = *(const bf16x8*)(q0 + 32 + quad * 8);

    f32x4 O[4];
    #pragma unroll
    for (int ht = 0; ht < 4; ++ht) O[ht] = f32x4{0.f, 0.f, 0.f, 0.f};
    float lrow[4] = {0.f, 0.f, 0.f, 0.f};

    const int trow = t0 + w * 16 + quad * 4;
    const int jt0 = c * CH;
    const int jt1 = (c == g) ? qt + 1 : (c + 1) * CH;

    const int drow = w * 8 + (lane >> 3);
    const int dsw  = ((lane & 7) ^ (drow & 7)) << 3;
    const bf16* kbase = kw + (long)b * T * H;
    const bf16* vbase = vtw + (long)b * H * T;
    const long koffA = (long)drow * H + dsw;
    const long koffB = koffA + 32 * H;
    const long voffA = (long)drow * T + dsw;
    const long voffB = voffA + (long)32 * T;

    {
        const long ks0 = (long)jt0 * 64;
        dma16(kbase + ks0 * H + koffA, &sK[0][w * 8][0]);
        dma16(kbase + ks0 * H + koffB, &sK[0][32 + w * 8][0]);
        dma16(vbase + ks0 + voffA, &sVt[0][w * 8][0]);
        dma16(vbase + ks0 + voffB, &sVt[0][32 + w * 8][0]);
    }
    __syncthreads();

    int buf = 0;
    for (int jt = jt0; jt < jt1; ++jt) {
        if (jt + 1 < jt1) {
            const long ksn = (long)(jt + 1) * 64;
            dma16(kbase + ksn * H + koffA, &sK[buf ^ 1][w * 8][0]);
            dma16(kbase + ksn * H + koffB, &sK[buf ^ 1][32 + w * 8][0]);
            dma16(vbase + ksn + voffA, &sVt[buf ^ 1][w * 8][0]);
            dma16(vbase + ksn + voffB, &sVt[buf ^ 1][32 + w * 8][0]);
        }

        const int s0 = jt * 64;
        const bool diag = (jt == qt);
        #pragma unroll
        for (int nt = 0; nt < 4; ++nt) {
            f32x4 sacc = f32x4{0.f, 0.f, 0.f, 0.f};
            sacc = MFMA16(aq0, *(const bf16x8*)&sK[buf][nt * 16 + ml][(quad ^ mx) << 3], sacc);
            sacc = MFMA16(aq1, *(const bf16x8*)&sK[buf][nt * 16 + ml][((4 + quad) ^ mx) << 3], sacc);
            const int col = s0 + nt * 16 + ml;
            #pragma unroll
            for (int rr = 0; rr < 4; ++rr) {
                const float p = (diag && col > trow + rr) ? 0.f : __expf(sacc[rr]);
                lrow[rr] += p;
                sP[w][quad * 4 + rr][nt * 16 + ml] = (bf16)p;
            }
        }
        asm volatile("s_waitcnt lgkmcnt(0)" ::: "memory");

        #pragma unroll
        for (int ks = 0; ks < 2; ++ks) {
            const bf16x8 ap = *(const bf16x8*)&sP[w][ml][ks * 32 + quad * 8];
            #pragma unroll
            for (int ht = 0; ht < 4; ++ht)
                O[ht] = MFMA16(ap,
                    *(const bf16x8*)&sVt[buf][ht * 16 + ml][(((ks << 2) + quad) ^ mx) << 3],
                    O[ht]);
        }

        __syncthreads();
        buf ^= 1;
    }

    #pragma unroll
    for (int d = 1; d < 16; d <<= 1)
        #pragma unroll
        for (int rr = 0; rr < 4; ++rr)
            lrow[rr] += __shfl_xor(lrow[rr], d, 64);

    const long slot = (long)b * SLOTS_PER_B + (long)(g + 1) * (4 * g + r) + c;
    float* po = pO + slot * 4096 + (w * 16) * 64;
    #pragma unroll
    for (int ht = 0; ht < 4; ++ht)
        #pragma unroll
        for (int rr = 0; rr < 4; ++rr)
            po[(quad * 4 + rr) * 64 + ht * 16 + ml] = O[ht][rr];
    if (ml == 0) {
        #pragma unroll
        for (int rr = 0; rr < 4; ++rr)
            pL[slot * 64 + w * 16 + quad * 4 + rr] = lrow[rr];
    }
}

// ---------------------------------------------------------------------------
// Kernel 4: combine partials. grid (64 qt, 4 b), 256 thr.
// ---------------------------------------------------------------------------
__global__ __launch_bounds__(256) void combine_kernel(const float* __restrict__ pO,
                                                      const float* __restrict__ pL,
                                                      float* __restrict__ out) {
    const int qt = blockIdx.x;
    const int b  = blockIdx.y;
    const int g  = qt >> 3, r = qt & 7;
    const int nch = g + 1;
    const long slot0 = (long)b * SLOTS_PER_B + (long)(g + 1) * (4 * g + r);

    const int tid = threadIdx.x;
    const int row = tid >> 2;
    const int q4  = tid & 3;

    f32x4 o[4];
    #pragma unroll
    for (int j = 0; j < 4; ++j) o[j] = f32x4{0.f, 0.f, 0.f, 0.f};
    float l = 0.f;

    for (int cc = 0; cc < nch; ++cc) {
        const float* po = pO + (slot0 + cc) * 4096 + row * 64 + q4 * 16;
        #pragma unroll
        for (int j = 0; j < 4; ++j) o[j] += *(const f32x4*)(po + j * 4);
        l += pL[(slot0 + cc) * 64 + row];
    }
    const float inv = 1.f / l;
    float* op = out + ((long)b * T + qt * 64 + row) * H + q4 * 16;
    #pragma unroll
    for (int j = 0; j < 4; ++j) {
        f32x4 v = o[j];
        v[0] *= inv; v[1] *= inv; v[2] *= inv; v[3] *= inv;
        *(f32x4*)(op + j * 4) = v;
    }
}

// ---------------------------------------------------------------------------
extern "C" void kernel_launch(void* const* d_in, const int* in_sizes, int n_in,
                              void* d_out, int out_size, void* d_ws, size_t ws_size,
                              hipStream_t stream) {
    const float* x  = (const float*)d_in[0];
    const float* Wq = (const float*)d_in[1];
    const float* Wk = (const float*)d_in[2];
    const float* Wv = (const float*)d_in[3];
    float* out = (float*)d_out;

    char* ws = (char*)d_ws;
    const size_t WT_BYTES = (size_t)NG * Cd * sizeof(bf16);
    const size_t QK_BYTES = (size_t)Bn * T * H * sizeof(bf16);
    const size_t PO_OFF   = WT_BYTES + 3 * QK_BYTES;
    const size_t PO_BYTES = (size_t)Bn * SLOTS_PER_B * 4096 * sizeof(float);
    bf16*  Wt  = (bf16*)ws;
    bf16*  qw  = (bf16*)(ws + WT_BYTES);
    bf16*  kw  = (bf16*)(ws + WT_BYTES + QK_BYTES);
    bf16*  vtw = (bf16*)(ws + WT_BYTES + 2 * QK_BYTES);
    float* pO  = (float*)(ws + PO_OFF);
    float* pL  = (float*)(ws + PO_OFF + PO_BYTES);

    wt_kernel<<<dim3(16, 3), dim3(256), 0, stream>>>(Wq, Wk, Wv, Wt);
    proj_kernel<<<dim3((Bn * T) / 32), dim3(512), 0, stream>>>(x, Wt, qw, kw, vtw);
    attn_kernel<<<dim3(T / 64, CH, Bn), dim3(256), 0, stream>>>(qw, kw, vtw, pO, pL);
    combine_kernel<<<dim3(T / 64, Bn), dim3(256), 0, stream>>>(pO, pL, out);
}